// Round 1
// baseline (502.066 us; speedup 1.0000x reference)
//
#include <hip/hip_runtime.h>
#include <math.h>

#define NROWS 4096
#define EDIM  1024
#define KNOISE 50
#define NORM_TERM 9.0f

// One block per row n. 4 waves/block; wave w handles indices k = w, w+4, ...
// over the 51 (target + 50 noise) gathered weight rows. Each wave:
//  - caches the input row in registers (lane l holds float4 chunks p*256+l*4)
//  - per index: coalesced float4 stream of the 4KB weight row, fma, 64-lane
//    butterfly reduce, lane0 does the exp/log term
//  - one atomicAdd per wave of -(sum of terms)/N into the scalar output.
__global__ __launch_bounds__(256) void nce_loss_kernel(
    const float* __restrict__ input,
    const int*   __restrict__ target,
    const int*   __restrict__ noise_samples,
    const float* __restrict__ noise,
    const float* __restrict__ weight,
    const float* __restrict__ bias,
    float*       __restrict__ out)
{
    const int n    = blockIdx.x;
    const int tid  = threadIdx.x;
    const int wave = tid >> 6;
    const int lane = tid & 63;

    const float4* inrow = (const float4*)(input + (size_t)n * EDIM);

    // Register-cache this lane's fragment of the input row (reused ~13x).
    float4 inv[4];
#pragma unroll
    for (int p = 0; p < 4; ++p)
        inv[p] = inrow[p * 64 + lane];

    float acc = 0.0f;

    for (int k = wave; k < KNOISE + 1; k += 4) {
        const int idx = (k == 0) ? target[n] : noise_samples[n * KNOISE + (k - 1)];
        const float4* wrow = (const float4*)(weight + (size_t)idx * EDIM);

        float dot = 0.0f;
#pragma unroll
        for (int p = 0; p < 4; ++p) {
            float4 w = wrow[p * 64 + lane];
            dot = fmaf(inv[p].x, w.x, dot);
            dot = fmaf(inv[p].y, w.y, dot);
            dot = fmaf(inv[p].z, w.z, dot);
            dot = fmaf(inv[p].w, w.w, dot);
        }

        // 64-lane butterfly reduction
#pragma unroll
        for (int off = 32; off > 0; off >>= 1)
            dot += __shfl_xor(dot, off, 64);

        if (lane == 0) {
            const float logit = dot + bias[idx];
            const float p     = __expf(logit - NORM_TERM);
            const float c     = (float)KNOISE * noise[idx];
            // k==0: rnn_loss = log(p/(p+c)); else: noise term = log(c/(p+c))
            const float num  = (k == 0) ? p : c;
            acc += __logf(num / (p + c));
        }
    }

    if (lane == 0)
        atomicAdd(out, -acc * (1.0f / (float)NROWS));
}

extern "C" void kernel_launch(void* const* d_in, const int* in_sizes, int n_in,
                              void* d_out, int out_size, void* d_ws, size_t ws_size,
                              hipStream_t stream) {
    const float* input         = (const float*)d_in[0];
    const int*   target        = (const int*)  d_in[1];
    const int*   noise_samples = (const int*)  d_in[2];
    const float* noise         = (const float*)d_in[3];
    const float* weight        = (const float*)d_in[4];
    const float* bias          = (const float*)d_in[5];
    float*       out           = (float*)d_out;

    // d_out is poisoned 0xAA before every timed launch; zero it (async, capture-safe).
    hipMemsetAsync(out, 0, sizeof(float), stream);

    nce_loss_kernel<<<NROWS, 256, 0, stream>>>(
        input, target, noise_samples, noise, weight, bias, out);
}

// Round 2
// 368.539 us; speedup vs baseline: 1.3623x; 1.3623x over previous
//
#include <hip/hip_runtime.h>
#include <math.h>

#define NROWS 4096
#define EDIM  1024
#define KNOISE 50
#define KTOT  51
#define NORM_TERM 9.0f
#define NSLOTS 256

// One block per row n, 4 waves/block. Wave w owns contiguous indices
// [13w, min(51, 13w+13)). Per iteration it processes a BATCH of 4 gathered
// weight rows: 16 independent float4 loads in flight (vs 4 in R1), scalar
// operands (bias/noise) prefetched before the row streams, 4 independent
// 64-lane butterflies, term math computed uniformly in all lanes (no
// divergent memory ops). Block-level partial goes to one of 256 ws slots
// (16 same-address atomics/slot max); a 1-block finish kernel sums them.
__global__ __launch_bounds__(256) void nce_main(
    const float* __restrict__ input,
    const int*   __restrict__ target,
    const int*   __restrict__ noise_samples,
    const float* __restrict__ noise,
    const float* __restrict__ weight,
    const float* __restrict__ bias,
    float*       __restrict__ partial)
{
    const int n    = blockIdx.x;
    const int tid  = threadIdx.x;
    const int wave = tid >> 6;
    const int lane = tid & 63;

    const float4* inrow = (const float4*)(input + (size_t)n * EDIM);
    float4 inv[4];
#pragma unroll
    for (int p = 0; p < 4; ++p)
        inv[p] = inrow[p * 64 + lane];

    const int start = wave * 13;
    const int end   = (start + 13 < KTOT) ? start + 13 : KTOT;

    float acc = 0.0f;
    int k = start;

    // ---- batched main loop: 4 gathered rows per iteration ----
    for (; k + 4 <= end; k += 4) {
        int idx[4];
#pragma unroll
        for (int i = 0; i < 4; ++i) {
            const int kk = k + i;
            idx[i] = (kk == 0) ? target[n] : noise_samples[n * KNOISE + kk - 1];
        }

        // prefetch scalar operands early (uniform-address broadcast loads)
        float bz[4], cz[4];
#pragma unroll
        for (int i = 0; i < 4; ++i) {
            bz[i] = bias[idx[i]];
            cz[i] = (float)KNOISE * noise[idx[i]];
        }

        // issue all 16 row loads before any FMA
        float4 wr[4][4];
#pragma unroll
        for (int i = 0; i < 4; ++i) {
            const float4* wrow = (const float4*)(weight + (size_t)idx[i] * EDIM);
#pragma unroll
            for (int p = 0; p < 4; ++p)
                wr[i][p] = wrow[p * 64 + lane];
        }

        float dot[4] = {0.f, 0.f, 0.f, 0.f};
#pragma unroll
        for (int i = 0; i < 4; ++i) {
#pragma unroll
            for (int p = 0; p < 4; ++p) {
                dot[i] = fmaf(inv[p].x, wr[i][p].x, dot[i]);
                dot[i] = fmaf(inv[p].y, wr[i][p].y, dot[i]);
                dot[i] = fmaf(inv[p].z, wr[i][p].z, dot[i]);
                dot[i] = fmaf(inv[p].w, wr[i][p].w, dot[i]);
            }
        }

        // 4 independent butterfly reductions (pipeline through DS unit)
#pragma unroll
        for (int off = 32; off > 0; off >>= 1) {
#pragma unroll
            for (int i = 0; i < 4; ++i)
                dot[i] += __shfl_xor(dot[i], off, 64);
        }

        // term math, uniform across lanes (all operands already resident)
#pragma unroll
        for (int i = 0; i < 4; ++i) {
            const float p   = __expf(dot[i] + bz[i] - NORM_TERM);
            const float num = (k + i == 0) ? p : cz[i];
            acc += __logf(num / (p + cz[i]));
        }
    }

    // ---- remainder (0 or 1 index) ----
    for (; k < end; ++k) {
        const int idx = (k == 0) ? target[n] : noise_samples[n * KNOISE + k - 1];
        const float bz = bias[idx];
        const float cz = (float)KNOISE * noise[idx];
        const float4* wrow = (const float4*)(weight + (size_t)idx * EDIM);
        float dot = 0.f;
#pragma unroll
        for (int p = 0; p < 4; ++p) {
            float4 w = wrow[p * 64 + lane];
            dot = fmaf(inv[p].x, w.x, dot);
            dot = fmaf(inv[p].y, w.y, dot);
            dot = fmaf(inv[p].z, w.z, dot);
            dot = fmaf(inv[p].w, w.w, dot);
        }
#pragma unroll
        for (int off = 32; off > 0; off >>= 1)
            dot += __shfl_xor(dot, off, 64);
        const float p   = __expf(dot + bz - NORM_TERM);
        const float num = (k == 0) ? p : cz;
        acc += __logf(num / (p + cz));
    }

    // ---- block reduce (acc is lane-uniform within each wave) ----
    __shared__ float warr[4];
    if (lane == 0) warr[wave] = acc;
    __syncthreads();
    if (tid == 0) {
        const float s = warr[0] + warr[1] + warr[2] + warr[3];
        atomicAdd(&partial[n & (NSLOTS - 1)], -s * (1.0f / (float)NROWS));
    }
}

__global__ __launch_bounds__(64) void nce_finish(const float* __restrict__ partial,
                                                 float* __restrict__ out)
{
    const int lane = threadIdx.x;
    float v = partial[lane] + partial[lane + 64] + partial[lane + 128] + partial[lane + 192];
#pragma unroll
    for (int off = 32; off > 0; off >>= 1)
        v += __shfl_xor(v, off, 64);
    if (lane == 0) out[0] = v;
}

extern "C" void kernel_launch(void* const* d_in, const int* in_sizes, int n_in,
                              void* d_out, int out_size, void* d_ws, size_t ws_size,
                              hipStream_t stream) {
    const float* input         = (const float*)d_in[0];
    const int*   target        = (const int*)  d_in[1];
    const int*   noise_samples = (const int*)  d_in[2];
    const float* noise         = (const float*)d_in[3];
    const float* weight        = (const float*)d_in[4];
    const float* bias          = (const float*)d_in[5];
    float*       out           = (float*)d_out;
    float*       partial       = (float*)d_ws;   // 256 f32 slots

    hipMemsetAsync(partial, 0, NSLOTS * sizeof(float), stream);

    nce_main<<<NROWS, 256, 0, stream>>>(
        input, target, noise_samples, noise, weight, bias, partial);
    nce_finish<<<1, 64, 0, stream>>>(partial, out);
}